// Round 10
// baseline (295.076 us; speedup 1.0000x reference)
//
#include <hip/hip_runtime.h>
#include <math.h>

// Problem constants (fixed by the reference setup)
#define NN 50000          // nodes
#define NE 800000         // edges (before self loops)
#define NTE (NE + NN)     // edges incl self loops
#define NG 16             // graphs
#define HID 128           // hidden/out dim (all layers out=128)
#define NEG_SLOPE 0.2f

#define EPW 4096          // edges per workgroup in scatter
#define NWG_E ((NTE + EPW - 1) / EPW)   // 208
#define GEMM_GRID ((NN + 63) / 64)      // 782 (BM=64 tiles)

#define SCAP 64           // per-node edge slot capacity (max deg ~40, Poisson(17))
#define NPART 64          // pool partial buffers (kills atomic contention)

typedef __attribute__((ext_vector_type(8))) __bf16 bf16x8;
typedef __attribute__((ext_vector_type(4))) float f32x4;

union V16 {
    float4 f4;
    uint4 u4;
    bf16x8 b8;
    __bf16 h[8];
};

// ---------------------------------------------------------------------------
// prep: zero deg/part + all three weight transposes, one dispatch.
// W [K][128] fp32 -> Wt [128][K] bf16, PRE-SWIZZLED: within each 128-col
// K-half, 16-B chunk q of row n is stored at chunk position q ^ (n&7)
// (pairs with the GEMM's linear global_load_lds staging + XOR ds_reads).
// ---------------------------------------------------------------------------
__global__ void k_prep(int* __restrict__ deg, float* __restrict__ part,
                       const float* __restrict__ W0, const float* __restrict__ W1,
                       const float* __restrict__ W2, __bf16* __restrict__ Wt0,
                       __bf16* __restrict__ Wt1, __bf16* __restrict__ Wt2) {
    int t = blockIdx.x * blockDim.x + threadIdx.x;
    if (t < NN) deg[t] = 0;
    if (t < NPART * NG * HID) part[t] = 0.0f;
    if (t < 256 * HID) {
        int k = t >> 7, n = t & 127;          // W0[k][n], k in 0..255
        int half = k >> 7;                    // K-half (0/1)
        int q = (k >> 3) & 15;                // 16-B chunk within half
        int e = k & 7;
        Wt0[(size_t)n * 256 + half * 128 + ((q ^ (n & 7)) << 3) + e] = (__bf16)W0[t];
    } else if (t < 256 * HID + HID * HID) {
        int u = t - 256 * HID;
        int k = u >> 7, n = u & 127;          // k in 0..127
        int q = k >> 3, e = k & 7;
        Wt1[(size_t)n * 128 + ((q ^ (n & 7)) << 3) + e] = (__bf16)W1[u];
    } else if (t < 256 * HID + 2 * HID * HID) {
        int u = t - 256 * HID - HID * HID;
        int k = u >> 7, n = u & 127;
        int q = k >> 3, e = k & 7;
        Wt2[(size_t)n * 128 + ((q ^ (n & 7)) << 3) + e] = (__bf16)W2[u];
    }
}

// ---------------------------------------------------------------------------
// Direct per-node slot scatter (replaces bucket CSR + k_bfill entirely):
// pos = atomicAdd(deg[dst]); slot[dst*SCAP+pos] = src (ushort, src < 2^16).
// 850K atomics over 50K counters = ~17/address, uncontended.
// ---------------------------------------------------------------------------
__device__ __forceinline__ void scatter_body(const int* __restrict__ ei,
                                             int* __restrict__ deg,
                                             unsigned short* __restrict__ slot,
                                             int blk) {
    int t = threadIdx.x;
    int base = blk * EPW;
    #pragma unroll
    for (int r = 0; r < EPW / 256; r++) {
        int idx = base + r * 256 + t;
        if (idx < NTE) {
            int src, dst;
            if (idx < NE) { src = ei[idx]; dst = ei[NE + idx]; }
            else          { src = idx - NE; dst = src; }
            int pos = atomicAdd(&deg[dst], 1);
            if (pos < SCAP)   // defensive; P(deg>64) ~ 1e-13
                slot[(size_t)dst * SCAP + pos] = (unsigned short)src;
        }
    }
}

// ---------------------------------------------------------------------------
// Hybrid MFMA GEMM  C[M x 128] = A[M x K] * B[K x 128].  (round-9, frozen)
// B half-panel: 32 KB unpadded LDS via global_load_lds (linear dest);
// bank conflicts avoided by the weight pre-swizzle + XOR ds_reads.
// A: per-lane 16-B fragments global->VGPR.
// ---------------------------------------------------------------------------
template <typename AT, int K>
__device__ __forceinline__ void gemm_body(const AT* __restrict__ A,
                                          const __bf16* __restrict__ Bt,
                                          __bf16* __restrict__ C,
                                          const float* __restrict__ a_s,
                                          const float* __restrict__ a_d,
                                          float* __restrict__ als,
                                          float* __restrict__ ald,
                                          int M, int blk) {
    __shared__ __align__(16) __bf16 Bs[128 * 128];   // 32 KB, linear

    int tid = threadIdx.x;
    int rowBase = blk * 64;
    int wv = tid >> 6;        // wave 0..3 -> rows wv*16..wv*16+15
    int lane = tid & 63;
    int g = lane >> 4;        // k-slice selector (0..3)
    int c = lane & 15;        // col-in-tile / row-in-tile selector

    int rowA = rowBase + wv * 16 + c;      // this lane's A row
    bool va = rowA < M;

    f32x4 acc[8];
    #pragma unroll
    for (int ni = 0; ni < 8; ni++) acc[ni] = (f32x4){0.f, 0.f, 0.f, 0.f};

    for (int kh = 0; kh < K; kh += 128) {
        if (kh) __syncthreads();   // protect Bs overwrite
        // async-stage B half-panel: 8 x global_load_lds(16B) per thread.
        #pragma unroll
        for (int rep = 0; rep < 8; rep++) {
            int ch = rep * 256 + tid;
            int r = ch >> 4, q = ch & 15;
            const __bf16* gp = Bt + (size_t)r * K + kh + q * 8;
            __bf16* lp = Bs + (size_t)(rep * 256 + (tid & 192)) * 8;
            __builtin_amdgcn_global_load_lds(gp, lp, 16, 0, 0);
        }
        // preload this half's A fragments (4 independent 16-B loads / lane)
        bf16x8 afr[4];
        #pragma unroll
        for (int kc = 0; kc < 4; kc++) {
            if constexpr (sizeof(AT) == 2) {
                V16 t;
                t.f4 = (float4){0.f, 0.f, 0.f, 0.f};
                if (va) t.f4 = *(const float4*)((const __bf16*)A + (size_t)rowA * K + kh + kc * 32 + g * 8);
                afr[kc] = t.b8;
            } else {
                float vv[8] = {0.f, 0.f, 0.f, 0.f, 0.f, 0.f, 0.f, 0.f};
                if (va) {
                    const float* Ap = (const float*)A + (size_t)rowA * K + kh + kc * 32 + g * 8;
                    float4 v0 = *(const float4*)Ap;
                    float4 v1 = *(const float4*)(Ap + 4);
                    vv[0] = v0.x; vv[1] = v0.y; vv[2] = v0.z; vv[3] = v0.w;
                    vv[4] = v1.x; vv[5] = v1.y; vv[6] = v1.z; vv[7] = v1.w;
                }
                V16 t;
                #pragma unroll
                for (int q = 0; q < 8; q++) t.h[q] = (__bf16)vv[q];
                afr[kc] = t.b8;
            }
        }
        __syncthreads();   // drains vmcnt (global_load_lds) before ds_read

        // 32-MFMA burst: B from LDS (swizzled chunk addressing), A from regs
        #pragma unroll
        for (int kc = 0; kc < 4; kc++) {
            #pragma unroll
            for (int ni = 0; ni < 8; ni++) {
                const __bf16* bp = Bs + (size_t)(ni * 16 + c) * 128 +
                                   (((kc * 4 + g) ^ (c & 7)) << 3);
                bf16x8 b = *(const bf16x8*)bp;
                acc[ni] = __builtin_amdgcn_mfma_f32_16x16x32_bf16(afr[kc], b, acc[ni], 0, 0, 0);
            }
        }
    }

    float asv[8], adv[8];
    #pragma unroll
    for (int ni = 0; ni < 8; ni++) {
        asv[ni] = a_s[ni * 16 + c];
        adv[ni] = a_d[ni * 16 + c];
    }
    int rb = rowBase + wv * 16 + g * 4;
    #pragma unroll
    for (int i = 0; i < 4; i++) {
        int row = rb + i;
        float s = 0.f, dd = 0.f;
        #pragma unroll
        for (int ni = 0; ni < 8; ni++) {
            float v = acc[ni][i];
            s = fmaf(v, asv[ni], s);
            dd = fmaf(v, adv[ni], dd);
        }
        #pragma unroll
        for (int o = 1; o <= 8; o <<= 1) {
            s += __shfl_xor(s, o);
            dd += __shfl_xor(dd, o);
        }
        if (row < M) {
            #pragma unroll
            for (int ni = 0; ni < 8; ni++)
                C[(size_t)row * HID + ni * 16 + c] = (__bf16)acc[ni][i];
            if (c == 0) {
                als[row] = s;
                ald[row] = dd;
            }
        }
    }
}

// standalone GEMM (layers 1-2, bf16 A, K=128 -> single half-panel)
__global__ __launch_bounds__(256, 4) void k_gemm_bf16(const __bf16* __restrict__ A,
                                                      const __bf16* __restrict__ Bt,
                                                      __bf16* __restrict__ C,
                                                      const float* __restrict__ a_s,
                                                      const float* __restrict__ a_d,
                                                      float* __restrict__ als,
                                                      float* __restrict__ ald) {
    gemm_body<__bf16, HID>(A, Bt, C, a_s, a_d, als, ald, NN, blockIdx.x);
}

// layer-0 GEMM (fp32 A, K=256) fused with per-node slot scatter (independent):
// blocks [0, GEMM_GRID) do GEMM, the rest do scatter.
__global__ __launch_bounds__(256, 4) void k_gemm0_scatter(const float* __restrict__ x,
                                                          const __bf16* __restrict__ Wt0,
                                                          __bf16* __restrict__ C,
                                                          const float* __restrict__ a_s,
                                                          const float* __restrict__ a_d,
                                                          float* __restrict__ als,
                                                          float* __restrict__ ald,
                                                          const int* __restrict__ ei,
                                                          int* __restrict__ deg,
                                                          unsigned short* __restrict__ slot) {
    if (blockIdx.x < GEMM_GRID) {
        gemm_body<float, 256>(x, Wt0, C, a_s, a_d, als, ald, NN, blockIdx.x);
    } else {
        scatter_body(ei, deg, slot, blockIdx.x - GEMM_GRID);
    }
}

// ---------------------------------------------------------------------------
// fused softmax + weighted gather (round-4 proven phases, frozen): one wave
// per dst node, edge list from per-node slot (deg <= SCAP always in practice).
// Phase 1: lane j handles edge j; (src, cf-bits) packed into one LDS int2,
//   zero-padded to 64 (pad slots contribute cf=0 * h[0] - exact).
// Phase 2: 16-lane edge groups (4 edges in flight), wave-uniform trip count.
// ---------------------------------------------------------------------------
__global__ __launch_bounds__(256) void k_attn(const __bf16* __restrict__ h,
                                              const float* __restrict__ als,
                                              const float* __restrict__ ald,
                                              const int* __restrict__ deg,
                                              const unsigned short* __restrict__ slot,
                                              const float* __restrict__ bias,
                                              __bf16* __restrict__ yout,
                                              int do_relu) {
    __shared__ int2 s_e[4][64];   // (src, cf bits) per wave
    int gt = blockIdx.x * blockDim.x + threadIdx.x;
    int d = gt >> 6;
    int lane = gt & 63;
    if (d >= NN) return;
    int wv = threadIdx.x >> 6;   // wave within block
    int grp = lane >> 4;         // edge slot 0..3
    int c = lane & 15;           // dim block (8 dims: c*8 .. c*8+7)

    int dg = deg[d];
    if (dg > SCAP) dg = SCAP;    // matches scatter's write clamp
    const unsigned short* sp = slot + (size_t)d * SCAP;
    float ald_d = ald[d];
    float acc[8] = {0.f, 0.f, 0.f, 0.f, 0.f, 0.f, 0.f, 0.f};

    // ---- phase 1: softmax ----
    int s = 0;
    float e = -INFINITY;
    if (lane < dg) {
        s = sp[lane];
        float t = als[s] + ald_d;
        e = (t > 0.0f) ? t : NEG_SLOPE * t;
    }
    float mx = e;
    #pragma unroll
    for (int o = 32; o > 0; o >>= 1) mx = fmaxf(mx, __shfl_xor(mx, o));
    float p = (lane < dg) ? __expf(e - mx) : 0.0f;
    float z = p;
    #pragma unroll
    for (int o = 32; o > 0; o >>= 1) z += __shfl_xor(z, o);
    float inv_z = 1.0f / z;          // self loop guarantees z > 0
    s_e[wv][lane] = make_int2(s, __float_as_int(p * inv_z));

    // ---- phase 2: gather, 4 edges in flight, wave-uniform trip count ----
    int degR = (dg + 3) & ~3;
    #pragma unroll 4
    for (int k = grp; k < degR; k += 4) {
        int2 pr = s_e[wv][k];        // uniform within 16-lane group
        int ss = pr.x;
        float cf = __int_as_float(pr.y);
        V16 v;
        v.f4 = *(const float4*)(h + (size_t)ss * HID + c * 8);
        #pragma unroll
        for (int i = 0; i < 4; i++) {
            unsigned int u = (&v.u4.x)[i];
            float lo = __uint_as_float(u << 16);
            float hi = __uint_as_float(u & 0xffff0000u);
            acc[2 * i]     = fmaf(cf, lo, acc[2 * i]);
            acc[2 * i + 1] = fmaf(cf, hi, acc[2 * i + 1]);
        }
    }

    // combine the 4 edge-groups
    #pragma unroll
    for (int t = 0; t < 8; t++) {
        acc[t] += __shfl_xor(acc[t], 16);
        acc[t] += __shfl_xor(acc[t], 32);
    }

    if (grp == 0) {
        float4 b0 = *(const float4*)(bias + c * 8);
        float4 b1 = *(const float4*)(bias + c * 8 + 4);
        acc[0] += b0.x; acc[1] += b0.y; acc[2] += b0.z; acc[3] += b0.w;
        acc[4] += b1.x; acc[5] += b1.y; acc[6] += b1.z; acc[7] += b1.w;
        if (do_relu) {
            #pragma unroll
            for (int t = 0; t < 8; t++) acc[t] = fmaxf(acc[t], 0.0f);
        }
        V16 o;
        #pragma unroll
        for (int t = 0; t < 8; t++) o.h[t] = (__bf16)acc[t];
        *(float4*)(yout + (size_t)d * HID + c * 8) = o.f4;
    }
}

// ---------------------------------------------------------------------------
// layer-2 attention: same phases; epilogue feeds the global mean pool via
// NPART partial buffers (blockIdx & 63), ~14 atomics/address.
// ---------------------------------------------------------------------------
__global__ __launch_bounds__(256) void k_attn_pool(const __bf16* __restrict__ h,
                                                   const float* __restrict__ als,
                                                   const float* __restrict__ ald,
                                                   const int* __restrict__ deg,
                                                   const unsigned short* __restrict__ slot,
                                                   const float* __restrict__ bias,
                                                   const int* __restrict__ batch,
                                                   float* __restrict__ part) {
    __shared__ int2 s_e[4][64];
    __shared__ float py[4][128];
    __shared__ int pg[4];
    int tid = threadIdx.x;
    int gt = blockIdx.x * blockDim.x + tid;
    int d = gt >> 6;              // grid covers exactly NN nodes
    int lane = gt & 63;
    int wv = tid >> 6;
    int grp = lane >> 4;
    int c = lane & 15;

    int dg = deg[d];
    if (dg > SCAP) dg = SCAP;
    const unsigned short* sp = slot + (size_t)d * SCAP;
    float ald_d = ald[d];
    float acc[8] = {0.f, 0.f, 0.f, 0.f, 0.f, 0.f, 0.f, 0.f};

    int s = 0;
    float e = -INFINITY;
    if (lane < dg) {
        s = sp[lane];
        float t = als[s] + ald_d;
        e = (t > 0.0f) ? t : NEG_SLOPE * t;
    }
    float mx = e;
    #pragma unroll
    for (int o = 32; o > 0; o >>= 1) mx = fmaxf(mx, __shfl_xor(mx, o));
    float p = (lane < dg) ? __expf(e - mx) : 0.0f;
    float z = p;
    #pragma unroll
    for (int o = 32; o > 0; o >>= 1) z += __shfl_xor(z, o);
    float inv_z = 1.0f / z;
    s_e[wv][lane] = make_int2(s, __float_as_int(p * inv_z));

    int degR = (dg + 3) & ~3;
    #pragma unroll 4
    for (int k = grp; k < degR; k += 4) {
        int2 pr = s_e[wv][k];
        int ss = pr.x;
        float cf = __int_as_float(pr.y);
        V16 v;
        v.f4 = *(const float4*)(h + (size_t)ss * HID + c * 8);
        #pragma unroll
        for (int i = 0; i < 4; i++) {
            unsigned int u = (&v.u4.x)[i];
            float lo = __uint_as_float(u << 16);
            float hi = __uint_as_float(u & 0xffff0000u);
            acc[2 * i]     = fmaf(cf, lo, acc[2 * i]);
            acc[2 * i + 1] = fmaf(cf, hi, acc[2 * i + 1]);
        }
    }

    #pragma unroll
    for (int t = 0; t < 8; t++) {
        acc[t] += __shfl_xor(acc[t], 16);
        acc[t] += __shfl_xor(acc[t], 32);
    }

    if (grp == 0) {
        float4 b0 = *(const float4*)(bias + c * 8);
        float4 b1 = *(const float4*)(bias + c * 8 + 4);
        acc[0] += b0.x; acc[1] += b0.y; acc[2] += b0.z; acc[3] += b0.w;
        acc[4] += b1.x; acc[5] += b1.y; acc[6] += b1.z; acc[7] += b1.w;
        // no relu on layer 2
        #pragma unroll
        for (int t = 0; t < 8; t++) py[wv][c * 8 + t] = acc[t];
        if (c == 0) pg[wv] = batch[d];
    }
    __syncthreads();
    if (tid < 128) {
        float* pp = part + (size_t)(blockIdx.x & (NPART - 1)) * NG * HID;
        float a = 0.0f;
        int gc = pg[0];
        #pragma unroll
        for (int n = 0; n < 4; n++) {
            int g = pg[n];
            if (g != gc) {
                atomicAdd(&pp[gc * HID + tid], a);
                a = 0.0f;
                gc = g;
            }
            a += py[n][tid];
        }
        atomicAdd(&pp[gc * HID + tid], a);
    }
}

// fold NPART partials + divide by counts (binary search on sorted batch)
__global__ void k_div(const float* __restrict__ part, const int* __restrict__ batch,
                      float* __restrict__ out) {
    int i = blockIdx.x * blockDim.x + threadIdx.x;
    if (i >= NG * HID) return;
    float s = 0.0f;
    #pragma unroll 8
    for (int p = 0; p < NPART; p++) s += part[(size_t)p * NG * HID + i];
    int g = i >> 7;
    int lo = 0, hi = NN;
    while (lo < hi) { int mid = (lo + hi) >> 1; if (batch[mid] < g) lo = mid + 1; else hi = mid; }
    int lo2 = lo, hi2 = NN;
    while (lo2 < hi2) { int mid = (lo2 + hi2) >> 1; if (batch[mid] < g + 1) lo2 = mid + 1; else hi2 = mid; }
    int c = lo2 - lo;
    out[i] = s / (float)(c > 1 ? c : 1);
}

// ---------------------------------------------------------------------------
extern "C" void kernel_launch(void* const* d_in, const int* in_sizes, int n_in,
                              void* d_out, int out_size, void* d_ws, size_t ws_size,
                              hipStream_t stream) {
    const float* x     = (const float*)d_in[0];   // [50000,256]
    const int*   ei    = (const int*)d_in[1];     // [2,800000]
    const int*   batch = (const int*)d_in[2];     // [50000]
    const float* W[3]  = {(const float*)d_in[3], (const float*)d_in[7], (const float*)d_in[11]};
    const float* AS[3] = {(const float*)d_in[4], (const float*)d_in[8], (const float*)d_in[12]};
    const float* AD[3] = {(const float*)d_in[5], (const float*)d_in[9], (const float*)d_in[13]};
    const float* BI[3] = {(const float*)d_in[6], (const float*)d_in[10], (const float*)d_in[14]};
    float* out = (float*)d_out;

    // workspace layout (~33 MB)
    char* ws = (char*)d_ws;
    size_t o = 0;
    auto alloc = [&](size_t bytes) {
        void* p = ws + o;
        o = (o + bytes + 255) & ~(size_t)255;
        return p;
    };
    __bf16* hb  = (__bf16*)alloc((size_t)NN * HID * 2);   // GEMM output (12.8 MB)
    __bf16* yb  = (__bf16*)alloc((size_t)NN * HID * 2);   // layer output bf16 (12.8 MB)
    __bf16* Wt0 = (__bf16*)alloc((size_t)256 * HID * 2);
    __bf16* Wt1 = (__bf16*)alloc((size_t)HID * HID * 2);
    __bf16* Wt2 = (__bf16*)alloc((size_t)HID * HID * 2);
    float* als  = (float*)alloc(NN * 4);
    float* ald  = (float*)alloc(NN * 4);
    int* deg    = (int*)alloc(NN * 4);
    unsigned short* slot = (unsigned short*)alloc((size_t)NN * SCAP * 2);  // 6.4 MB
    float* part = (float*)alloc((size_t)NPART * NG * HID * 4);             // 512 KB
    (void)ws_size; (void)in_sizes; (void)n_in; (void)out_size;

    const int attn_grid = (NN * 64 + 255) / 256; // 12500, one wave per node

    // ---- prep: zero deg/part + swizzled weight transposes ----
    k_prep<<<(NPART * NG * HID + 255) / 256, 256, 0, stream>>>(
        deg, part, W[0], W[1], W[2], Wt0, Wt1, Wt2);

    // ---- layer-0 GEMM fused with per-node slot scatter (independent work) ----
    k_gemm0_scatter<<<GEMM_GRID + NWG_E, 256, 0, stream>>>(
        x, Wt0, hb, AS[0], AD[0], als, ald, ei, deg, slot);

    // ---- layer 0 attention ----
    k_attn<<<attn_grid, 256, 0, stream>>>(hb, als, ald, deg, slot, BI[0], yb, 1);

    // ---- layer 1 ----
    k_gemm_bf16<<<GEMM_GRID, 256, 0, stream>>>(yb, Wt1, hb, AS[1], AD[1], als, ald);
    k_attn<<<attn_grid, 256, 0, stream>>>(hb, als, ald, deg, slot, BI[1], yb, 1);

    // ---- layer 2 ----
    k_gemm_bf16<<<GEMM_GRID, 256, 0, stream>>>(yb, Wt2, hb, AS[2], AD[2], als, ald);
    // layer-2 attention fused with global mean pool (partial buffers)
    k_attn_pool<<<attn_grid, 256, 0, stream>>>(hb, als, ald, deg, slot, BI[2],
                                               batch, part);

    // ---- finalize mean (fold partials) ----
    k_div<<<(NG * HID + 255) / 256, 256, 0, stream>>>(part, batch, out);
}

// Round 11
// 277.696 us; speedup vs baseline: 1.0626x; 1.0626x over previous
//
#include <hip/hip_runtime.h>
#include <math.h>

// Problem constants (fixed by the reference setup)
#define NN 50000          // nodes
#define NE 800000         // edges (before self loops)
#define NTE (NE + NN)     // edges incl self loops
#define NG 16             // graphs
#define HID 128           // hidden/out dim (all layers out=128)
#define NEG_SLOPE 0.2f

#define NBUK 391          // ceil(NN/128) buckets of 128 dst nodes
#define SLOT 2560         // per-bucket slot capacity (mean 2174, sd 47 -> +8 sigma)
#define EPW 4096          // edges per workgroup in scatter
#define NWG_E ((NTE + EPW - 1) / EPW)   // 208
#define GEMM_GRID ((NN + 63) / 64)      // 782 (BM=64 tiles)

#define NPART 64          // pool partial buffers (kills atomic contention)

// B half-panel LDS: 128 rows x 136 bf16 = 34816 B -> 4 blocks/CU
#define BPAD 136
#define SMEM_BYTES 34816

typedef __attribute__((ext_vector_type(8))) __bf16 bf16x8;
typedef __attribute__((ext_vector_type(4))) float f32x4;

union V16 {
    float4 f4;
    uint4 u4;
    bf16x8 b8;
    __bf16 h[8];
};

// ---------------------------------------------------------------------------
// prep: zero bwr/part + all three weight transposes + off[NN], one dispatch.
// W [K][128] fp32 -> Wt [128][K] bf16
// ---------------------------------------------------------------------------
__global__ void k_prep(int* __restrict__ bwr, float* __restrict__ part,
                       int* __restrict__ off,
                       const float* __restrict__ W0, const float* __restrict__ W1,
                       const float* __restrict__ W2, __bf16* __restrict__ Wt0,
                       __bf16* __restrict__ Wt1, __bf16* __restrict__ Wt2) {
    int t = blockIdx.x * blockDim.x + threadIdx.x;
    if (t == 0) off[NN] = NTE;
    if (t <= NBUK) bwr[t] = 0;
    if (t < NPART * NG * HID) part[t] = 0.0f;
    if (t < 256 * HID) {
        int k = t >> 7, n = t & 127;
        Wt0[(size_t)n * 256 + k] = (__bf16)W0[t];
    } else if (t < 256 * HID + HID * HID) {
        int u = t - 256 * HID;
        int k = u >> 7, n = u & 127;
        Wt1[(size_t)n * HID + k] = (__bf16)W1[u];
    } else if (t < 256 * HID + 2 * HID * HID) {
        int u = t - 256 * HID - HID * HID;
        int k = u >> 7, n = u & 127;
        Wt2[(size_t)n * HID + k] = (__bf16)W2[u];
    }
}

// ---------------------------------------------------------------------------
// Slotted CSR scatter: per-block LDS hist -> chunk reservation via bwr
// allocator -> packed record write into bucket slot (coalesced chunk writes;
// the direct per-node-slot variant was 35x write-amplified — round 10).
// rec[b*SLOT + i] = src | (dst&127)<<17.
// ---------------------------------------------------------------------------
__device__ __forceinline__ void scatter_body(const int* __restrict__ ei,
                                             int* __restrict__ bwr,
                                             int* __restrict__ rec, int blk,
                                             char* smem) {
    int* hist = (int*)smem;          // NBUK ints
    int* cur = hist + NBUK;          // NBUK ints
    int t = threadIdx.x;
    for (int b = t; b < NBUK; b += 256) hist[b] = 0;
    __syncthreads();
    int base = blk * EPW;
    #pragma unroll
    for (int r = 0; r < EPW / 256; r++) {
        int idx = base + r * 256 + t;
        if (idx < NTE) {
            int dst = (idx < NE) ? ei[NE + idx] : (idx - NE);
            atomicAdd(&hist[dst >> 7], 1);
        }
    }
    __syncthreads();
    for (int b = t; b < NBUK; b += 256) {
        int c = hist[b];
        if (c) cur[b] = atomicAdd(&bwr[b], c);   // chunk start within slot b
    }
    __syncthreads();
    #pragma unroll
    for (int r = 0; r < EPW / 256; r++) {
        int idx = base + r * 256 + t;
        if (idx < NTE) {
            int src, dst;
            if (idx < NE) { src = ei[idx]; dst = ei[NE + idx]; }
            else          { src = idx - NE; dst = src; }
            int b = dst >> 7;
            int pos = atomicAdd(&cur[b], 1);
            rec[(size_t)b * SLOT + pos] = src | ((dst & 127) << 17);
        }
    }
}

// inclusive 512-scan of bwr into s[] (LDS), 256 threads. s[i] = sum bwr[0..i].
__device__ __forceinline__ void scan512(const int* __restrict__ bwr, int* s) {
    int t = threadIdx.x;
    s[t] = (t < NBUK) ? bwr[t] : 0;
    s[t + 256] = (t + 256 < NBUK) ? bwr[t + 256] : 0;
    __syncthreads();
    for (int o = 1; o < 512; o <<= 1) {
        int a0 = (t >= o) ? s[t - o] : 0;
        int a1 = s[t + 256 - o];          // t+256 >= o always (o <= 256)
        __syncthreads();
        s[t] += a0;
        s[t + 256] += a1;
        __syncthreads();
    }
}

// one workgroup per bucket: scan bwr -> packed base, local 128-scan -> off[],
// compact slotted rec into packed csr
__global__ __launch_bounds__(256) void k_bfill(const int* __restrict__ bwr,
                                               const int* __restrict__ rec,
                                               int* __restrict__ off,
                                               int* __restrict__ csr) {
    __shared__ int s[512];
    __shared__ int cnt[128];
    __shared__ int scn[128];
    __shared__ int cur[128];
    int b = blockIdx.x, t = threadIdx.x;
    scan512(bwr, s);
    int base = s[b] - bwr[b];              // exclusive prefix (uniform)
    int n = bwr[b];
    const int* rb = rec + (size_t)b * SLOT;
    if (t < 128) cnt[t] = 0;
    __syncthreads();
    for (int i = t; i < n; i += 256) atomicAdd(&cnt[rb[i] >> 17], 1);
    __syncthreads();
    if (t < 128) scn[t] = cnt[t];
    __syncthreads();
    #pragma unroll
    for (int o = 1; o < 128; o <<= 1) {
        int add = (t >= o && t < 128) ? scn[t - o] : 0;
        __syncthreads();
        if (t < 128) scn[t] += add;
        __syncthreads();
    }
    if (t < 128) {
        int ex = scn[t] - cnt[t];
        cur[t] = ex;
        int d = b * 128 + t;
        if (d < NN) off[d] = base + ex;
    }
    __syncthreads();
    for (int i = t; i < n; i += 256) {
        int r = rb[i];
        int dloc = r >> 17;
        int src = r & 131071;
        int pos = atomicAdd(&cur[dloc], 1);
        csr[base + pos] = src;
    }
}

// ---------------------------------------------------------------------------
// Hybrid MFMA GEMM  C[M x 128] = A[M x K] * B[K x 128].
// B (shared by all blocks) -> LDS half-panel [128][128] bf16, one barrier per
// half.  A (streamed, zero reuse) -> per-lane 16-B fragments loaded DIRECTLY
// global->VGPR, preloaded before the barrier (independent, pipelined).
// LDS = 34.8 KB -> 4 blocks/CU; __launch_bounds__(256,4) allows 128 VGPRs.
// Fused epilogue: als[row]=dot(Crow,a_s), ald[row]=dot(Crow,a_d)
// ---------------------------------------------------------------------------
template <typename AT, int K>
__device__ __forceinline__ void gemm_body(const AT* __restrict__ A,
                                          const __bf16* __restrict__ Bt,
                                          __bf16* __restrict__ C,
                                          const float* __restrict__ a_s,
                                          const float* __restrict__ a_d,
                                          float* __restrict__ als,
                                          float* __restrict__ ald,
                                          int M, int blk, char* smem) {
    __bf16(*Bs)[BPAD] = (__bf16(*)[BPAD])smem;   // [128][136]

    int tid = threadIdx.x;
    int rowBase = blk * 64;
    int wv = tid >> 6;        // wave 0..3 -> rows wv*16..wv*16+15
    int lane = tid & 63;
    int g = lane >> 4;        // k-slice selector (0..3)
    int c = lane & 15;        // col-in-tile / row-in-tile selector

    int rowA = rowBase + wv * 16 + c;      // this lane's A row
    bool va = rowA < M;

    f32x4 acc[8];
    #pragma unroll
    for (int ni = 0; ni < 8; ni++) acc[ni] = (f32x4){0.f, 0.f, 0.f, 0.f};

    for (int kh = 0; kh < K; kh += 128) {
        if (kh) __syncthreads();   // protect Bs overwrite
        // stage B half-panel [128][128] (8 x 16-B chunks per thread)
        #pragma unroll
        for (int rep = 0; rep < 8; rep++) {
            int ch = rep * 256 + tid;
            int r = ch >> 4, q = ch & 15;
            *(float4*)&Bs[r][q * 8] = *(const float4*)(Bt + (size_t)r * K + kh + q * 8);
        }
        // preload this half's A fragments (4 independent 16-B loads / lane)
        bf16x8 afr[4];
        #pragma unroll
        for (int kc = 0; kc < 4; kc++) {
            if constexpr (sizeof(AT) == 2) {
                V16 t;
                t.f4 = (float4){0.f, 0.f, 0.f, 0.f};
                if (va) t.f4 = *(const float4*)((const __bf16*)A + (size_t)rowA * K + kh + kc * 32 + g * 8);
                afr[kc] = t.b8;
            } else {
                float vv[8] = {0.f, 0.f, 0.f, 0.f, 0.f, 0.f, 0.f, 0.f};
                if (va) {
                    const float* Ap = (const float*)A + (size_t)rowA * K + kh + kc * 32 + g * 8;
                    float4 v0 = *(const float4*)Ap;
                    float4 v1 = *(const float4*)(Ap + 4);
                    vv[0] = v0.x; vv[1] = v0.y; vv[2] = v0.z; vv[3] = v0.w;
                    vv[4] = v1.x; vv[5] = v1.y; vv[6] = v1.z; vv[7] = v1.w;
                }
                V16 t;
                #pragma unroll
                for (int q = 0; q < 8; q++) t.h[q] = (__bf16)vv[q];
                afr[kc] = t.b8;
            }
        }
        __syncthreads();

        // 32-MFMA burst: B from LDS, A from registers
        #pragma unroll
        for (int kc = 0; kc < 4; kc++) {
            #pragma unroll
            for (int ni = 0; ni < 8; ni++) {
                bf16x8 b = *(const bf16x8*)&Bs[ni * 16 + c][kc * 32 + g * 8];
                acc[ni] = __builtin_amdgcn_mfma_f32_16x16x32_bf16(afr[kc], b, acc[ni], 0, 0, 0);
            }
        }
    }

    float asv[8], adv[8];
    #pragma unroll
    for (int ni = 0; ni < 8; ni++) {
        asv[ni] = a_s[ni * 16 + c];
        adv[ni] = a_d[ni * 16 + c];
    }
    int rb = rowBase + wv * 16 + g * 4;
    #pragma unroll
    for (int i = 0; i < 4; i++) {
        int row = rb + i;
        float s = 0.f, dd = 0.f;
        #pragma unroll
        for (int ni = 0; ni < 8; ni++) {
            float v = acc[ni][i];
            s = fmaf(v, asv[ni], s);
            dd = fmaf(v, adv[ni], dd);
        }
        #pragma unroll
        for (int o = 1; o <= 8; o <<= 1) {
            s += __shfl_xor(s, o);
            dd += __shfl_xor(dd, o);
        }
        if (row < M) {
            #pragma unroll
            for (int ni = 0; ni < 8; ni++)
                C[(size_t)row * HID + ni * 16 + c] = (__bf16)acc[ni][i];
            if (c == 0) {
                als[row] = s;
                ald[row] = dd;
            }
        }
    }
}

// standalone GEMM (layers 1-2, bf16 A, K=128 -> single half-panel)
__global__ __launch_bounds__(256, 4) void k_gemm_bf16(const __bf16* __restrict__ A,
                                                      const __bf16* __restrict__ Bt,
                                                      __bf16* __restrict__ C,
                                                      const float* __restrict__ a_s,
                                                      const float* __restrict__ a_d,
                                                      float* __restrict__ als,
                                                      float* __restrict__ ald) {
    __shared__ __align__(16) char smem[SMEM_BYTES];
    gemm_body<__bf16, HID>(A, Bt, C, a_s, a_d, als, ald, NN, blockIdx.x, smem);
}

// layer-0 GEMM (fp32 A, K=256, two half-panels) fused with slotted CSR
// scatter (independent): blocks [0, GEMM_GRID) do GEMM, the rest do scatter.
__global__ __launch_bounds__(256, 4) void k_gemm0_scatter(const float* __restrict__ x,
                                                          const __bf16* __restrict__ Wt0,
                                                          __bf16* __restrict__ C,
                                                          const float* __restrict__ a_s,
                                                          const float* __restrict__ a_d,
                                                          float* __restrict__ als,
                                                          float* __restrict__ ald,
                                                          const int* __restrict__ ei,
                                                          int* __restrict__ bwr,
                                                          int* __restrict__ rec) {
    __shared__ __align__(16) char smem[SMEM_BYTES];
    if (blockIdx.x < GEMM_GRID) {
        gemm_body<float, 256>(x, Wt0, C, a_s, a_d, als, ald, NN, blockIdx.x, smem);
    } else {
        scatter_body(ei, bwr, rec, blockIdx.x - GEMM_GRID, smem);
    }
}

// ---------------------------------------------------------------------------
// fused softmax + weighted gather (round-4 proven structure, frozen):
// one wave per dst node.
// ---------------------------------------------------------------------------
__global__ __launch_bounds__(256) void k_attn(const __bf16* __restrict__ h,
                                              const float* __restrict__ als,
                                              const float* __restrict__ ald,
                                              const int* __restrict__ off,
                                              const int* __restrict__ csr,
                                              const float* __restrict__ bias,
                                              __bf16* __restrict__ yout,
                                              int do_relu) {
    __shared__ int2 s_e[4][64];   // (src, cf bits) per wave
    int gt = blockIdx.x * blockDim.x + threadIdx.x;
    int d = gt >> 6;
    int lane = gt & 63;
    if (d >= NN) return;
    int wv = threadIdx.x >> 6;   // wave within block
    int grp = lane >> 4;         // edge slot 0..3
    int c = lane & 15;           // dim block (8 dims: c*8 .. c*8+7)

    int e0 = off[d], e1 = off[d + 1];
    int deg = e1 - e0;
    float ald_d = ald[d];
    float acc[8] = {0.f, 0.f, 0.f, 0.f, 0.f, 0.f, 0.f, 0.f};

    if (deg <= 64) {
        // ---- phase 1: softmax ----
        int s = 0;
        float e = -INFINITY;
        if (lane < deg) {
            s = csr[e0 + lane];
            float t = als[s] + ald_d;
            e = (t > 0.0f) ? t : NEG_SLOPE * t;
        }
        float mx = e;
        #pragma unroll
        for (int o = 32; o > 0; o >>= 1) mx = fmaxf(mx, __shfl_xor(mx, o));
        float p = (lane < deg) ? __expf(e - mx) : 0.0f;
        float z = p;
        #pragma unroll
        for (int o = 32; o > 0; o >>= 1) z += __shfl_xor(z, o);
        float inv_z = 1.0f / z;          // self loop guarantees z > 0
        s_e[wv][lane] = make_int2(s, __float_as_int(p * inv_z));

        // ---- phase 2: gather, 4 edges in flight, wave-uniform trip count ----
        int degR = (deg + 3) & ~3;
        #pragma unroll 4
        for (int k = grp; k < degR; k += 4) {
            int2 pr = s_e[wv][k];        // uniform within 16-lane group
            int ss = pr.x;
            float cf = __int_as_float(pr.y);
            V16 v;
            v.f4 = *(const float4*)(h + (size_t)ss * HID + c * 8);
            #pragma unroll
            for (int i = 0; i < 4; i++) {
                unsigned int u = (&v.u4.x)[i];
                float lo = __uint_as_float(u << 16);
                float hi = __uint_as_float(u & 0xffff0000u);
                acc[2 * i]     = fmaf(cf, lo, acc[2 * i]);
                acc[2 * i + 1] = fmaf(cf, hi, acc[2 * i + 1]);
            }
        }
    } else {
        // ---- rare slow path: strided two-pass + per-edge recompute ----
        float mx = -INFINITY;
        for (int j = e0 + lane; j < e1; j += 64) {
            float t = als[csr[j]] + ald_d;
            t = (t > 0.0f) ? t : NEG_SLOPE * t;
            mx = fmaxf(mx, t);
        }
        #pragma unroll
        for (int o = 32; o > 0; o >>= 1) mx = fmaxf(mx, __shfl_xor(mx, o));
        float z = 0.0f;
        for (int j = e0 + lane; j < e1; j += 64) {
            float t = als[csr[j]] + ald_d;
            t = (t > 0.0f) ? t : NEG_SLOPE * t;
            z += __expf(t - mx);
        }
        #pragma unroll
        for (int o = 32; o > 0; o >>= 1) z += __shfl_xor(z, o);
        float inv_z = 1.0f / z;
        for (int k = grp; k < deg; k += 4) {
            int ss = csr[e0 + k];
            float t = als[ss] + ald_d;
            t = (t > 0.0f) ? t : NEG_SLOPE * t;
            float cf = __expf(t - mx) * inv_z;
            V16 v;
            v.f4 = *(const float4*)(h + (size_t)ss * HID + c * 8);
            #pragma unroll
            for (int i = 0; i < 4; i++) {
                unsigned int u = (&v.u4.x)[i];
                float lo = __uint_as_float(u << 16);
                float hi = __uint_as_float(u & 0xffff0000u);
                acc[2 * i]     = fmaf(cf, lo, acc[2 * i]);
                acc[2 * i + 1] = fmaf(cf, hi, acc[2 * i + 1]);
            }
        }
    }

    // combine the 4 edge-groups
    #pragma unroll
    for (int t = 0; t < 8; t++) {
        acc[t] += __shfl_xor(acc[t], 16);
        acc[t] += __shfl_xor(acc[t], 32);
    }

    if (grp == 0) {
        float4 b0 = *(const float4*)(bias + c * 8);
        float4 b1 = *(const float4*)(bias + c * 8 + 4);
        acc[0] += b0.x; acc[1] += b0.y; acc[2] += b0.z; acc[3] += b0.w;
        acc[4] += b1.x; acc[5] += b1.y; acc[6] += b1.z; acc[7] += b1.w;
        if (do_relu) {
            #pragma unroll
            for (int t = 0; t < 8; t++) acc[t] = fmaxf(acc[t], 0.0f);
        }
        V16 o;
        #pragma unroll
        for (int t = 0; t < 8; t++) o.h[t] = (__bf16)acc[t];
        *(float4*)(yout + (size_t)d * HID + c * 8) = o.f4;
    }
}

// ---------------------------------------------------------------------------
// layer-2 attention: same phases as k_attn; epilogue feeds the global mean
// pool via NPART partial buffers (blockIdx & 63), ~14 atomics/address.
// ---------------------------------------------------------------------------
__global__ __launch_bounds__(256) void k_attn_pool(const __bf16* __restrict__ h,
                                                   const float* __restrict__ als,
                                                   const float* __restrict__ ald,
                                                   const int* __restrict__ off,
                                                   const int* __restrict__ csr,
                                                   const float* __restrict__ bias,
                                                   const int* __restrict__ batch,
                                                   float* __restrict__ part) {
    __shared__ int2 s_e[4][64];
    __shared__ float py[4][128];
    __shared__ int pg[4];
    int tid = threadIdx.x;
    int gt = blockIdx.x * blockDim.x + tid;
    int d = gt >> 6;              // grid covers exactly NN nodes
    int lane = gt & 63;
    int wv = tid >> 6;
    int grp = lane >> 4;
    int c = lane & 15;

    int e0 = off[d], e1 = off[d + 1];
    int deg = e1 - e0;
    float ald_d = ald[d];
    float acc[8] = {0.f, 0.f, 0.f, 0.f, 0.f, 0.f, 0.f, 0.f};

    if (deg <= 64) {
        int s = 0;
        float e = -INFINITY;
        if (lane < deg) {
            s = csr[e0 + lane];
            float t = als[s] + ald_d;
            e = (t > 0.0f) ? t : NEG_SLOPE * t;
        }
        float mx = e;
        #pragma unroll
        for (int o = 32; o > 0; o >>= 1) mx = fmaxf(mx, __shfl_xor(mx, o));
        float p = (lane < deg) ? __expf(e - mx) : 0.0f;
        float z = p;
        #pragma unroll
        for (int o = 32; o > 0; o >>= 1) z += __shfl_xor(z, o);
        float inv_z = 1.0f / z;
        s_e[wv][lane] = make_int2(s, __float_as_int(p * inv_z));

        int degR = (deg + 3) & ~3;
        #pragma unroll 4
        for (int k = grp; k < degR; k += 4) {
            int2 pr = s_e[wv][k];
            int ss = pr.x;
            float cf = __int_as_float(pr.y);
            V16 v;
            v.f4 = *(const float4*)(h + (size_t)ss * HID + c * 8);
            #pragma unroll
            for (int i = 0; i < 4; i++) {
                unsigned int u = (&v.u4.x)[i];
                float lo = __uint_as_float(u << 16);
                float hi = __uint_as_float(u & 0xffff0000u);
                acc[2 * i]     = fmaf(cf, lo, acc[2 * i]);
                acc[2 * i + 1] = fmaf(cf, hi, acc[2 * i + 1]);
            }
        }
    } else {
        float mx = -INFINITY;
        for (int j = e0 + lane; j < e1; j += 64) {
            float t = als[csr[j]] + ald_d;
            t = (t > 0.0f) ? t : NEG_SLOPE * t;
            mx = fmaxf(mx, t);
        }
        #pragma unroll
        for (int o = 32; o > 0; o >>= 1) mx = fmaxf(mx, __shfl_xor(mx, o));
        float z = 0.0f;
        for (int j = e0 + lane; j < e1; j += 64) {
            float t = als[csr[j]] + ald_d;
            t = (t > 0.0f) ? t : NEG_SLOPE * t;
            z += __expf(t - mx);
        }
        #pragma unroll
        for (int o = 32; o > 0; o >>= 1) z += __shfl_xor(z, o);
        float inv_z = 1.0f / z;
        for (int k = grp; k < deg; k += 4) {
            int ss = csr[e0 + k];
            float t = als[ss] + ald_d;
            t = (t > 0.0f) ? t : NEG_SLOPE * t;
            float cf = __expf(t - mx) * inv_z;
            V16 v;
            v.f4 = *(const float4*)(h + (size_t)ss * HID + c * 8);
            #pragma unroll
            for (int i = 0; i < 4; i++) {
                unsigned int u = (&v.u4.x)[i];
                float lo = __uint_as_float(u << 16);
                float hi = __uint_as_float(u & 0xffff0000u);
                acc[2 * i]     = fmaf(cf, lo, acc[2 * i]);
                acc[2 * i + 1] = fmaf(cf, hi, acc[2 * i + 1]);
            }
        }
    }

    #pragma unroll
    for (int t = 0; t < 8; t++) {
        acc[t] += __shfl_xor(acc[t], 16);
        acc[t] += __shfl_xor(acc[t], 32);
    }

    if (grp == 0) {
        float4 b0 = *(const float4*)(bias + c * 8);
        float4 b1 = *(const float4*)(bias + c * 8 + 4);
        acc[0] += b0.x; acc[1] += b0.y; acc[2] += b0.z; acc[3] += b0.w;
        acc[4] += b1.x; acc[5] += b1.y; acc[6] += b1.z; acc[7] += b1.w;
        // no relu on layer 2
        #pragma unroll
        for (int t = 0; t < 8; t++) py[wv][c * 8 + t] = acc[t];
        if (c == 0) pg[wv] = batch[d];
    }
    __syncthreads();
    if (tid < 128) {
        float* pp = part + (size_t)(blockIdx.x & (NPART - 1)) * NG * HID;
        float a = 0.0f;
        int gc = pg[0];
        #pragma unroll
        for (int n = 0; n < 4; n++) {
            int g = pg[n];
            if (g != gc) {
                atomicAdd(&pp[gc * HID + tid], a);
                a = 0.0f;
                gc = g;
            }
            a += py[n][tid];
        }
        atomicAdd(&pp[gc * HID + tid], a);
    }
}

// fold NPART partials + divide by counts (binary search on sorted batch)
__global__ void k_div(const float* __restrict__ part, const int* __restrict__ batch,
                      float* __restrict__ out) {
    int i = blockIdx.x * blockDim.x + threadIdx.x;
    if (i >= NG * HID) return;
    float s = 0.0f;
    #pragma unroll 8
    for (int p = 0; p < NPART; p++) s += part[(size_t)p * NG * HID + i];
    int g = i >> 7;
    int lo = 0, hi = NN;
    while (lo < hi) { int mid = (lo + hi) >> 1; if (batch[mid] < g) lo = mid + 1; else hi = mid; }
    int lo2 = lo, hi2 = NN;
    while (lo2 < hi2) { int mid = (lo2 + hi2) >> 1; if (batch[mid] < g + 1) lo2 = mid + 1; else hi2 = mid; }
    int c = lo2 - lo;
    out[i] = s / (float)(c > 1 ? c : 1);
}

// ---------------------------------------------------------------------------
extern "C" void kernel_launch(void* const* d_in, const int* in_sizes, int n_in,
                              void* d_out, int out_size, void* d_ws, size_t ws_size,
                              hipStream_t stream) {
    const float* x     = (const float*)d_in[0];   // [50000,256]
    const int*   ei    = (const int*)d_in[1];     // [2,800000]
    const int*   batch = (const int*)d_in[2];     // [50000]
    const float* W[3]  = {(const float*)d_in[3], (const float*)d_in[7], (const float*)d_in[11]};
    const float* AS[3] = {(const float*)d_in[4], (const float*)d_in[8], (const float*)d_in[12]};
    const float* AD[3] = {(const float*)d_in[5], (const float*)d_in[9], (const float*)d_in[13]};
    const float* BI[3] = {(const float*)d_in[6], (const float*)d_in[10], (const float*)d_in[14]};
    float* out = (float*)d_out;

    // workspace layout (~33 MB)
    char* ws = (char*)d_ws;
    size_t o = 0;
    auto alloc = [&](size_t bytes) {
        void* p = ws + o;
        o = (o + bytes + 255) & ~(size_t)255;
        return p;
    };
    __bf16* hb  = (__bf16*)alloc((size_t)NN * HID * 2);   // GEMM output (12.8 MB)
    __bf16* yb  = (__bf16*)alloc((size_t)NN * HID * 2);   // layer output bf16 (12.8 MB)
    __bf16* Wt0 = (__bf16*)alloc((size_t)256 * HID * 2);
    __bf16* Wt1 = (__bf16*)alloc((size_t)HID * HID * 2);
    __bf16* Wt2 = (__bf16*)alloc((size_t)HID * HID * 2);
    float* als  = (float*)alloc(NN * 4);
    float* ald  = (float*)alloc(NN * 4);
    int* off    = (int*)alloc((NN + 1) * 4);
    int* bwr    = (int*)alloc((NBUK + 1) * 4);
    int* rec    = (int*)alloc((size_t)NBUK * SLOT * 4);   // slotted records (4 MB)
    int* csr    = (int*)alloc((size_t)NTE * 4);
    float* part = (float*)alloc((size_t)NPART * NG * HID * 4);  // 512 KB
    (void)ws_size; (void)in_sizes; (void)n_in; (void)out_size;

    const int attn_grid = (NN * 64 + 255) / 256; // 12500, one wave per node

    // ---- prep: zero init + weight transposes + off[NN] (one dispatch) ----
    k_prep<<<(NPART * NG * HID + 255) / 256, 256, 0, stream>>>(
        bwr, part, off, W[0], W[1], W[2], Wt0, Wt1, Wt2);

    // ---- layer-0 GEMM fused with slotted CSR scatter (independent work) ----
    k_gemm0_scatter<<<GEMM_GRID + NWG_E, 256, 0, stream>>>(
        x, Wt0, hb, AS[0], AD[0], als, ald, ei, bwr, rec);

    // ---- CSR finalize ----
    k_bfill<<<NBUK, 256, 0, stream>>>(bwr, rec, off, csr);

    // ---- layer 0 attention ----
    k_attn<<<attn_grid, 256, 0, stream>>>(hb, als, ald, off, csr, BI[0], yb, 1);

    // ---- layer 1 ----
    k_gemm_bf16<<<GEMM_GRID, 256, 0, stream>>>(yb, Wt1, hb, AS[1], AD[1], als, ald);
    k_attn<<<attn_grid, 256, 0, stream>>>(hb, als, ald, off, csr, BI[1], yb, 1);

    // ---- layer 2 ----
    k_gemm_bf16<<<GEMM_GRID, 256, 0, stream>>>(yb, Wt2, hb, AS[2], AD[2], als, ald);
    // layer-2 attention fused with global mean pool (partial buffers)
    k_attn_pool<<<attn_grid, 256, 0, stream>>>(hb, als, ald, off, csr, BI[2],
                                               batch, part);

    // ---- finalize mean (fold partials) ----
    k_div<<<(NG * HID + 255) / 256, 256, 0, stream>>>(part, batch, out);
}